// Round 21
// baseline (140.606 us; speedup 1.0000x reference)
//
#include <hip/hip_runtime.h>

namespace {
constexpr int N_NODES = 100000;
constexpr int N_EDGES = 640000;
constexpr int ROWTILES = N_NODES / 16;          // 6250 (exact)
constexpr int FILLBLK = (N_EDGES + 255) / 256;  // 2500
constexpr int GEMM1BLK = (ROWTILES + 3) / 4;    // 1563
constexpr int UGRID = 13 * 313;                 // 4069: 8 fill + 5 gemm per 13
constexpr int CAP = 16;                         // slots/node = one 64B line
constexpr int SPILL_CAP = 65536;
}

typedef short bf16x8 __attribute__((ext_vector_type(8)));
typedef float f32x4 __attribute__((ext_vector_type(4)));

static __device__ inline uint32_t cvt_pk_bf16(float a, float b) {
  uint32_t r;
  asm volatile("v_cvt_pk_bf16_f32 %0, %1, %2" : "=v"(r) : "v"(a), "v"(b));
  return r;  // lo = bf16(a) RNE, hi = bf16(b)
}

// 8 bf16 (uint4) -> 8 f32
static __device__ inline void bf8_to_f32(uint4 u, float* v) {
  v[0] = __uint_as_float(u.x << 16);
  v[1] = __uint_as_float(u.x & 0xffff0000u);
  v[2] = __uint_as_float(u.y << 16);
  v[3] = __uint_as_float(u.y & 0xffff0000u);
  v[4] = __uint_as_float(u.z << 16);
  v[5] = __uint_as_float(u.z & 0xffff0000u);
  v[6] = __uint_as_float(u.w << 16);
  v[7] = __uint_as_float(u.w & 0xffff0000u);
}

static __device__ inline uint4 f32_to_bf8(const float* v) {
  uint4 o;
  o.x = cvt_pk_bf16(v[0], v[1]);
  o.y = cvt_pk_bf16(v[2], v[3]);
  o.z = cvt_pk_bf16(v[4], v[5]);
  o.w = cvt_pk_bf16(v[6], v[7]);
  return o;
}

// ---------------- W prep fragments ----------------
// frag (ks, nt): lane l holds W[ks*32 + (l>>4)*8 + j][nt*16 + (l&15)], j=0..7,
// u32[p] = cvt_pk(w[2p], w[2p+1]) — identical (lane, elem)->k map as the A side.

static __device__ inline void wpack(const float* __restrict__ W, int kout, int idx,
                                    uint4* __restrict__ wfrag) {
  int nt_cnt = kout / 16;
  int lane = idx & 63;
  int nt = (idx >> 6) % nt_cnt;
  int ks = idx / (64 * nt_cnt);
  int g = lane >> 4, c = lane & 15;
  const float* wp = W + (ks * 32 + g * 8) * kout + nt * 16 + c;
  float w[8];
#pragma unroll
  for (int j = 0; j < 8; ++j) w[j] = wp[j * kout];
  wfrag[idx] = f32_to_bf8(w);
}

__global__ void k_wprep(const float* __restrict__ W1, const float* __restrict__ W2,
                        uint4* __restrict__ wf1, uint4* __restrict__ wf2) {
  int idx = blockIdx.x * 256 + threadIdx.x;
  if (idx < 2048) {
    wpack(W1, 128, idx, wf1);
  } else if (idx < 3072) {
    wpack(W2, 64, idx - 2048, wf2);
  }
}

// ---------------- UNION: hist+fill ∥ layer-1 GEMM, INTERLEAVED ----------------
// Roles interleaved 8:5 across blockIdx so every CU holds a mix (r18: -24 µs).
// pos = atomicAdd(&deg[c],1) is BOTH histogram and slot ticket (csr16 fixed
// layout). gemm1 writes hs1 unscaled -> deg-independent -> legal same-dispatch.

__global__ __launch_bounds__(256) void k_histfill_gemm1(
    const int* __restrict__ erow, const int* __restrict__ ecol,
    int* __restrict__ deg, int* __restrict__ csr16, int* __restrict__ nspill,
    int2* __restrict__ spill, const float* __restrict__ X,
    const uint4* __restrict__ wfrag, unsigned short* __restrict__ Yb) {
  const int tid = threadIdx.x;
  const int group = blockIdx.x / 13;
  const int pos = blockIdx.x % 13;

  if (pos < 8) {
    const int fb = group * 8 + pos;
    if (fb >= FILLBLK) return;
    int e = fb * 256 + tid;
    if (e < N_EDGES) {
      int c = ecol[e];
      int p = atomicAdd(&deg[c], 1);
      if (p < CAP) {
        __builtin_nontemporal_store(erow[e], &csr16[c * CAP + p]);
      } else {
        int si = atomicAdd(nspill, 1);
        if (si < SPILL_CAP) {
          __builtin_nontemporal_store(erow[e], &spill[si].x);
          __builtin_nontemporal_store(c, &spill[si].y);
        }
      }
    }
    return;
  }

  // ---- GEMM1: hs1[n,:] = bf16( x[n,:] @ W1 )  (unscaled, deg-independent) ----
  const int gb = group * 5 + (pos - 8);
  if (gb >= GEMM1BLK) return;
  const int wv = gb * 4 + (tid >> 6);
  if (wv >= ROWTILES) return;
  const int lane = tid & 63;
  const int g = lane >> 4, c = lane & 15;
  const int rb = wv * 16;

  constexpr int NT = 8;
  f32x4 acc[NT];
#pragma unroll
  for (int nt = 0; nt < NT; ++nt) acc[nt] = (f32x4){0.f, 0.f, 0.f, 0.f};

  const bf16x8* wf = (const bf16x8*)wfrag;
  const float* xrow = X + (long long)(rb + c) * 128 + g * 8;

#pragma unroll
  for (int ks = 0; ks < 4; ++ks) {
    float4 a0 = *(const float4*)(xrow + ks * 32);
    float4 a1 = *(const float4*)(xrow + ks * 32 + 4);
    union { bf16x8 v; uint32_t u[4]; } af;
    af.u[0] = cvt_pk_bf16(a0.x, a0.y);
    af.u[1] = cvt_pk_bf16(a0.z, a0.w);
    af.u[2] = cvt_pk_bf16(a1.x, a1.y);
    af.u[3] = cvt_pk_bf16(a1.z, a1.w);
#pragma unroll
    for (int nt = 0; nt < NT; ++nt) {
      bf16x8 bf = wf[(ks * NT + nt) * 64 + lane];
      acc[nt] = __builtin_amdgcn_mfma_f32_16x16x32_bf16(af.v, bf, acc[nt], 0, 0, 0);
    }
  }

  // C/D layout (m89-verified): col = lane&15, row = (lane>>4)*4 + reg
#pragma unroll
  for (int r = 0; r < 4; ++r) {
    int row = rb + g * 4 + r;
#pragma unroll
    for (int nt = 0; nt < NT; ++nt) {
      float val = acc[nt][r];
      Yb[(long long)row * 128 + nt * 16 + c] = (unsigned short)cvt_pk_bf16(val, val);
    }
  }
}

// ---------------- FUSED: layer-1 aggregation + layer-2 GEMM ----------------
// FOUR WAVES per stripe: wave w = edge slots {w, w+4, w+8, w+12}; wave 0 also
// self + spill. Quarters the serial gather chain per wave, 4x gathering waves
// (latency-bound: r19/r20 showed ~const latency per gathered row). Waves 1-3
// deposit partials in padded LDS; one barrier; wave 0 combines + MFMA tail.

__global__ __launch_bounds__(256) void k_gather_gemm2(
    const int* __restrict__ deg, const int* __restrict__ csr16,
    const int* __restrict__ nspill, const int2* __restrict__ spill,
    const unsigned short* __restrict__ hs1, const float* __restrict__ b1,
    const uint4* __restrict__ wfrag2, unsigned short* __restrict__ hs2) {
  __shared__ float part[3][64][33];  // waves 1-3 partials; +1 pad
  const int tid = threadIdx.x;
  const int wid = tid >> 6;  // 0..3
  const int lane = tid & 63;
  const int g = lane >> 4, c = lane & 15;
  const int rb = blockIdx.x * 16;
  const int n = rb + c;
  const int dg = deg[n];
  const int m = min(dg, CAP);
  const int base16 = n * CAP;
  const float d = rsqrtf((float)dg + 1.0f);

  float acc[4][8];
  if (wid == 0) {  // self term, scaled by d
    const unsigned short* hrow = hs1 + (long long)n * 128 + g * 8;
#pragma unroll
    for (int ks = 0; ks < 4; ++ks) {
      float v[8];
      bf8_to_f32(*(const uint4*)(hrow + ks * 32), v);
#pragma unroll
      for (int t = 0; t < 8; ++t) acc[ks][t] = d * v[t];
    }
  } else {
#pragma unroll
    for (int ks = 0; ks < 4; ++ks)
#pragma unroll
      for (int t = 0; t < 8; ++t) acc[ks][t] = 0.f;
  }

  // this wave's edge slots: wid, wid+4, wid+8, wid+12 (< m); unroll 2
  int j = wid;
  for (; j + 4 < m; j += 8) {
    int s0 = csr16[base16 + j], s1 = csr16[base16 + j + 4];
    float d0 = rsqrtf((float)deg[s0] + 1.0f);
    float d1 = rsqrtf((float)deg[s1] + 1.0f);
    const unsigned short* p0 = hs1 + (long long)s0 * 128 + g * 8;
    const unsigned short* p1 = hs1 + (long long)s1 * 128 + g * 8;
#pragma unroll
    for (int ks = 0; ks < 4; ++ks) {
      float v0[8], v1[8];
      bf8_to_f32(*(const uint4*)(p0 + ks * 32), v0);
      bf8_to_f32(*(const uint4*)(p1 + ks * 32), v1);
#pragma unroll
      for (int t = 0; t < 8; ++t)
        acc[ks][t] = fmaf(d1, v1[t], fmaf(d0, v0[t], acc[ks][t]));
    }
  }
  if (j < m) {
    int s0 = csr16[base16 + j];
    float d0 = rsqrtf((float)deg[s0] + 1.0f);
    const unsigned short* p0 = hs1 + (long long)s0 * 128 + g * 8;
#pragma unroll
    for (int ks = 0; ks < 4; ++ks) {
      float v0[8];
      bf8_to_f32(*(const uint4*)(p0 + ks * 32), v0);
#pragma unroll
      for (int t = 0; t < 8; ++t) acc[ks][t] = fmaf(d0, v0[t], acc[ks][t]);
    }
  }
  if (wid == 0 && dg > CAP) {  // rare: spill scan
    int ns = min(*nspill, SPILL_CAP);
    for (int i = 0; i < ns; ++i) {
      int2 p = spill[i];
      if (p.y == n) {
        float d0 = rsqrtf((float)deg[p.x] + 1.0f);
        const unsigned short* p0 = hs1 + (long long)p.x * 128 + g * 8;
#pragma unroll
        for (int ks = 0; ks < 4; ++ks) {
          float v0[8];
          bf8_to_f32(*(const uint4*)(p0 + ks * 32), v0);
#pragma unroll
          for (int t = 0; t < 8; ++t) acc[ks][t] = fmaf(d0, v0[t], acc[ks][t]);
        }
      }
    }
  }

  // combine: waves 1-3 -> LDS, wave 0 adds
  if (wid >= 1) {
#pragma unroll
    for (int ks = 0; ks < 4; ++ks)
#pragma unroll
      for (int t = 0; t < 8; ++t) part[wid - 1][lane][ks * 8 + t] = acc[ks][t];
  }
  __syncthreads();
  if (wid >= 1) return;
#pragma unroll
  for (int w = 0; w < 3; ++w)
#pragma unroll
    for (int ks = 0; ks < 4; ++ks)
#pragma unroll
      for (int t = 0; t < 8; ++t) acc[ks][t] += part[w][lane][ks * 8 + t];

  // agg1 row slice = relu(b1 + d*acc) -> bf16 A-fragments
  union { bf16x8 v; uint32_t u[4]; } av[4];
#pragma unroll
  for (int ks = 0; ks < 4; ++ks) {
    float4 bv0 = *(const float4*)&b1[ks * 32 + g * 8];
    float4 bv1 = *(const float4*)&b1[ks * 32 + g * 8 + 4];
    float r8[8];
    r8[0] = fmaxf(bv0.x + d * acc[ks][0], 0.f);
    r8[1] = fmaxf(bv0.y + d * acc[ks][1], 0.f);
    r8[2] = fmaxf(bv0.z + d * acc[ks][2], 0.f);
    r8[3] = fmaxf(bv0.w + d * acc[ks][3], 0.f);
    r8[4] = fmaxf(bv1.x + d * acc[ks][4], 0.f);
    r8[5] = fmaxf(bv1.y + d * acc[ks][5], 0.f);
    r8[6] = fmaxf(bv1.z + d * acc[ks][6], 0.f);
    r8[7] = fmaxf(bv1.w + d * acc[ks][7], 0.f);
    av[ks].u[0] = cvt_pk_bf16(r8[0], r8[1]);
    av[ks].u[1] = cvt_pk_bf16(r8[2], r8[3]);
    av[ks].u[2] = cvt_pk_bf16(r8[4], r8[5]);
    av[ks].u[3] = cvt_pk_bf16(r8[6], r8[7]);
  }

  // layer-2 MFMA: hs2 stripe = dinv * (agg1 @ W2)   (hs2 pre-scaled)
  f32x4 accm[4];
#pragma unroll
  for (int nt = 0; nt < 4; ++nt) accm[nt] = (f32x4){0.f, 0.f, 0.f, 0.f};
  const bf16x8* wf = (const bf16x8*)wfrag2;
#pragma unroll
  for (int ks = 0; ks < 4; ++ks) {
#pragma unroll
    for (int nt = 0; nt < 4; ++nt) {
      bf16x8 bf = wf[(ks * 4 + nt) * 64 + lane];
      accm[nt] = __builtin_amdgcn_mfma_f32_16x16x32_bf16(av[ks].v, bf, accm[nt], 0, 0, 0);
    }
  }

#pragma unroll
  for (int r = 0; r < 4; ++r) {
    int row = rb + g * 4 + r;
    float sc = rsqrtf((float)deg[row] + 1.0f);
#pragma unroll
    for (int nt = 0; nt < 4; ++nt) {
      float val = accm[nt][r] * sc;
      hs2[(long long)row * 64 + nt * 16 + c] = (unsigned short)cvt_pk_bf16(val, val);
    }
  }
}

// ---- final gather: out[n] = b2 + d_n*(hs2[n] + sum_src hs2[src]), f32 out ----
// hs2 rows pre-scaled by their own dinv -> no per-src scale here.

__global__ __launch_bounds__(256) void k_gather_out(
    const int* __restrict__ deg, const int* __restrict__ csr16,
    const int* __restrict__ nspill, const int2* __restrict__ spill,
    const unsigned short* __restrict__ hs, const float* __restrict__ bias,
    float* __restrict__ out) {
  constexpr int C = 64, Q = 8;
  int idx = blockIdx.x * 256 + threadIdx.x;
  if (idx >= N_NODES * Q) return;
  int n = idx / Q, q = idx % Q;
  int dg = deg[n];
  int m = min(dg, CAP);
  int base16 = n * CAP;
  float d = rsqrtf((float)dg + 1.0f);

  float acc[8];
  bf8_to_f32(*(const uint4*)&hs[(long long)n * C + q * 8], acc);  // self

  int j = 0;
  for (; j + 2 <= m; j += 2) {
    int s0 = csr16[base16 + j], s1 = csr16[base16 + j + 1];
    uint4 u0 = *(const uint4*)&hs[(long long)s0 * C + q * 8];
    uint4 u1 = *(const uint4*)&hs[(long long)s1 * C + q * 8];
    float v0[8], v1[8];
    bf8_to_f32(u0, v0);
    bf8_to_f32(u1, v1);
#pragma unroll
    for (int t = 0; t < 8; ++t) acc[t] += v0[t] + v1[t];
  }
  if (j < m) {
    float v0[8];
    bf8_to_f32(*(const uint4*)&hs[(long long)csr16[base16 + j] * C + q * 8], v0);
#pragma unroll
    for (int t = 0; t < 8; ++t) acc[t] += v0[t];
  }
  if (dg > CAP) {
    int ns = min(*nspill, SPILL_CAP);
    for (int i = 0; i < ns; ++i) {
      int2 p = spill[i];
      if (p.y == n) {
        float v0[8];
        bf8_to_f32(*(const uint4*)&hs[(long long)p.x * C + q * 8], v0);
#pragma unroll
        for (int t = 0; t < 8; ++t) acc[t] += v0[t];
      }
    }
  }

  float4 bv0 = *(const float4*)&bias[q * 8];
  float4 bv1 = *(const float4*)&bias[q * 8 + 4];
  float4 o0 = {bv0.x + d * acc[0], bv0.y + d * acc[1], bv0.z + d * acc[2],
               bv0.w + d * acc[3]};
  float4 o1 = {bv1.x + d * acc[4], bv1.y + d * acc[5], bv1.z + d * acc[6],
               bv1.w + d * acc[7]};
  *(float4*)&out[(long long)n * C + q * 8] = o0;
  *(float4*)&out[(long long)n * C + q * 8 + 4] = o1;
}

// ---------------- launch (1 memset + 4 dispatches) ----------------

extern "C" void kernel_launch(void* const* d_in, const int* in_sizes, int n_in,
                              void* d_out, int out_size, void* d_ws, size_t ws_size,
                              hipStream_t stream) {
  const float* x = (const float*)d_in[0];
  const int* ei = (const int*)d_in[1];
  const int* erow = ei;            // sources
  const int* ecol = ei + N_EDGES;  // targets
  const float* W1 = (const float*)d_in[2];
  const float* b1 = (const float*)d_in[3];
  const float* W2 = (const float*)d_in[4];
  const float* b2 = (const float*)d_in[5];
  float* out = (float*)d_out;

  char* ws = (char*)d_ws;
  // deg + nspill contiguous -> one memset
  int* deg = (int*)(ws + 0);                      // 400,000 B
  int* nspill = (int*)(ws + 400000);              // 64 B
  int* csr16 = (int*)(ws + 400064);               // 6,400,000 B (64B-aligned)
  int2* spill = (int2*)(ws + 6800064);            // 524,288 B
  unsigned short* hs1 = (unsigned short*)(ws + 7324352);   // 25.6 MB (bf16)
  unsigned short* hs2 = (unsigned short*)(ws + 32924352);  // 12.8 MB (bf16)
  uint4* wfrag1 = (uint4*)(ws + 45724352);        // 32 KB
  uint4* wfrag2 = (uint4*)(ws + 45757120);        // 16 KB

  // 0: zero deg+nspill
  hipMemsetAsync(deg, 0, 400064, stream);
  // 1: W fragment packing (must precede gemm1)
  k_wprep<<<12, 256, 0, stream>>>(W1, W2, wfrag1, wfrag2);
  // 2: hist+fill ∥ layer-1 GEMM, roles interleaved 8:5
  k_histfill_gemm1<<<UGRID, 256, 0, stream>>>(erow, ecol, deg, csr16, nspill, spill, x,
                                              wfrag1, hs1);
  // 3: fused layer-1 aggregation + layer-2 GEMM; 4 waves / stripe
  k_gather_gemm2<<<ROWTILES, 256, 0, stream>>>(deg, csr16, nspill, spill, hs1, b1,
                                               wfrag2, hs2);
  // 4: final aggregation -> out (f32)
  k_gather_out<<<N_NODES * 8 / 256, 256, 0, stream>>>(deg, csr16, nspill, spill, hs2,
                                                      b2, out);
}

// Round 22
// 123.331 us; speedup vs baseline: 1.1401x; 1.1401x over previous
//
#include <hip/hip_runtime.h>

namespace {
constexpr int N_NODES = 100000;
constexpr int N_EDGES = 640000;
constexpr int ROWTILES = N_NODES / 16;          // 6250 (exact)
constexpr int FILLBLK = N_EDGES / 1024;         // 625 (4 edges/thread, exact)
constexpr int GEMM1BLK = (ROWTILES + 3) / 4;    // 1563
constexpr int UGRID = 7 * 313;                  // 2191: 2 fill + 5 gemm per 7
constexpr int CAP = 16;                         // slots/node = one 64B line
constexpr int SPILL_CAP = 65536;
}

typedef short bf16x8 __attribute__((ext_vector_type(8)));
typedef float f32x4 __attribute__((ext_vector_type(4)));

static __device__ inline uint32_t cvt_pk_bf16(float a, float b) {
  uint32_t r;
  asm volatile("v_cvt_pk_bf16_f32 %0, %1, %2" : "=v"(r) : "v"(a), "v"(b));
  return r;  // lo = bf16(a) RNE, hi = bf16(b)
}

// 8 bf16 (uint4) -> 8 f32
static __device__ inline void bf8_to_f32(uint4 u, float* v) {
  v[0] = __uint_as_float(u.x << 16);
  v[1] = __uint_as_float(u.x & 0xffff0000u);
  v[2] = __uint_as_float(u.y << 16);
  v[3] = __uint_as_float(u.y & 0xffff0000u);
  v[4] = __uint_as_float(u.z << 16);
  v[5] = __uint_as_float(u.z & 0xffff0000u);
  v[6] = __uint_as_float(u.w << 16);
  v[7] = __uint_as_float(u.w & 0xffff0000u);
}

static __device__ inline uint4 f32_to_bf8(const float* v) {
  uint4 o;
  o.x = cvt_pk_bf16(v[0], v[1]);
  o.y = cvt_pk_bf16(v[2], v[3]);
  o.z = cvt_pk_bf16(v[4], v[5]);
  o.w = cvt_pk_bf16(v[6], v[7]);
  return o;
}

// ---------------- W prep fragments + workspace zeroing ----------------
// frag (ks, nt): lane l holds W[ks*32 + (l>>4)*8 + j][nt*16 + (l&15)], j=0..7,
// u32[p] = cvt_pk(w[2p], w[2p+1]) — identical (lane, elem)->k map as the A side.
// Also zeroes deg+nspill (stream order makes it visible to the next dispatch).

static __device__ inline void wpack(const float* __restrict__ W, int kout, int idx,
                                    uint4* __restrict__ wfrag) {
  int nt_cnt = kout / 16;
  int lane = idx & 63;
  int nt = (idx >> 6) % nt_cnt;
  int ks = idx / (64 * nt_cnt);
  int g = lane >> 4, c = lane & 15;
  const float* wp = W + (ks * 32 + g * 8) * kout + nt * 16 + c;
  float w[8];
#pragma unroll
  for (int j = 0; j < 8; ++j) w[j] = wp[j * kout];
  wfrag[idx] = f32_to_bf8(w);
}

__global__ void k_wprep_zero(const float* __restrict__ W1, const float* __restrict__ W2,
                             uint4* __restrict__ wf1, uint4* __restrict__ wf2,
                             int* __restrict__ deg_zero_base) {
  int idx = blockIdx.x * 256 + threadIdx.x;
  if (idx < 2048) {
    wpack(W1, 128, idx, wf1);
  } else if (idx < 3072) {
    wpack(W2, 64, idx - 2048, wf2);
  }
  int z = idx - 3072;
  if (z >= 0 && z < N_NODES + 16) deg_zero_base[z] = 0;  // deg + nspill
}

// ---------------- UNION: hist+fill ∥ layer-1 GEMM, INTERLEAVED ----------------
// Roles interleaved 2:5 across blockIdx so every CU holds a mix (r18: -24 µs).
// Fill: 4 edges/thread via int4 loads -> 4 independent atomic->store chains
// in flight per lane (fill is latency-bound). pos = atomicAdd(&deg[c],1) is
// BOTH histogram and slot ticket. gemm1 writes hs1 unscaled (deg-independent).

__global__ __launch_bounds__(256) void k_histfill_gemm1(
    const int* __restrict__ erow, const int* __restrict__ ecol,
    int* __restrict__ deg, int* __restrict__ csr16, int* __restrict__ nspill,
    int2* __restrict__ spill, const float* __restrict__ X,
    const uint4* __restrict__ wfrag, unsigned short* __restrict__ Yb) {
  const int tid = threadIdx.x;
  const int group = blockIdx.x / 7;
  const int pos = blockIdx.x % 7;

  if (pos < 2) {
    const int fb = group * 2 + pos;
    if (fb >= FILLBLK) return;
    const int e4 = fb * 256 + tid;  // exact: FILLBLK*256*4 == N_EDGES
    int4 r4 = *(const int4*)&erow[e4 * 4];
    int4 c4 = *(const int4*)&ecol[e4 * 4];
    int rs[4] = {r4.x, r4.y, r4.z, r4.w};
    int cs[4] = {c4.x, c4.y, c4.z, c4.w};
#pragma unroll
    for (int k = 0; k < 4; ++k) {
      int p = atomicAdd(&deg[cs[k]], 1);
      if (p < CAP) {
        __builtin_nontemporal_store(rs[k], &csr16[cs[k] * CAP + p]);
      } else {
        int si = atomicAdd(nspill, 1);
        if (si < SPILL_CAP) {
          __builtin_nontemporal_store(rs[k], &spill[si].x);
          __builtin_nontemporal_store(cs[k], &spill[si].y);
        }
      }
    }
    return;
  }

  // ---- GEMM1: hs1[n,:] = bf16( x[n,:] @ W1 )  (unscaled, deg-independent) ----
  const int gb = group * 5 + (pos - 2);
  if (gb >= GEMM1BLK) return;
  const int wv = gb * 4 + (tid >> 6);
  if (wv >= ROWTILES) return;
  const int lane = tid & 63;
  const int g = lane >> 4, c = lane & 15;
  const int rb = wv * 16;

  constexpr int NT = 8;
  f32x4 acc[NT];
#pragma unroll
  for (int nt = 0; nt < NT; ++nt) acc[nt] = (f32x4){0.f, 0.f, 0.f, 0.f};

  const bf16x8* wf = (const bf16x8*)wfrag;
  const float* xrow = X + (long long)(rb + c) * 128 + g * 8;

#pragma unroll
  for (int ks = 0; ks < 4; ++ks) {
    float4 a0 = *(const float4*)(xrow + ks * 32);
    float4 a1 = *(const float4*)(xrow + ks * 32 + 4);
    union { bf16x8 v; uint32_t u[4]; } af;
    af.u[0] = cvt_pk_bf16(a0.x, a0.y);
    af.u[1] = cvt_pk_bf16(a0.z, a0.w);
    af.u[2] = cvt_pk_bf16(a1.x, a1.y);
    af.u[3] = cvt_pk_bf16(a1.z, a1.w);
#pragma unroll
    for (int nt = 0; nt < NT; ++nt) {
      bf16x8 bf = wf[(ks * NT + nt) * 64 + lane];
      acc[nt] = __builtin_amdgcn_mfma_f32_16x16x32_bf16(af.v, bf, acc[nt], 0, 0, 0);
    }
  }

  // C/D layout (m89-verified): col = lane&15, row = (lane>>4)*4 + reg
#pragma unroll
  for (int r = 0; r < 4; ++r) {
    int row = rb + g * 4 + r;
#pragma unroll
    for (int nt = 0; nt < NT; ++nt) {
      float val = acc[nt][r];
      Yb[(long long)row * 128 + nt * 16 + c] = (unsigned short)cvt_pk_bf16(val, val);
    }
  }
}

// ---------------- FUSED: layer-1 aggregation + layer-2 GEMM ----------------
// TWO WAVES per stripe (r20 sweet spot): wave 0 = even slots + self + spill,
// wave 1 = odd slots. One LDS combine + one barrier; wave 0 runs MFMA tail.
// hs1 unscaled -> per-src rsqrtf(deg+1) scale.

__global__ __launch_bounds__(128) void k_gather_gemm2(
    const int* __restrict__ deg, const int* __restrict__ csr16,
    const int* __restrict__ nspill, const int2* __restrict__ spill,
    const unsigned short* __restrict__ hs1, const float* __restrict__ b1,
    const uint4* __restrict__ wfrag2, unsigned short* __restrict__ hs2) {
  __shared__ float part[64][33];  // wave-1 partials; +1 pad: conflict-free
  const int tid = threadIdx.x;
  const int wid = tid >> 6;  // 0 or 1
  const int lane = tid & 63;
  const int g = lane >> 4, c = lane & 15;
  const int rb = blockIdx.x * 16;
  const int n = rb + c;
  const int dg = deg[n];
  const int m = min(dg, CAP);
  const int base16 = n * CAP;
  const float d = rsqrtf((float)dg + 1.0f);

  float acc[4][8];
  if (wid == 0) {  // self term, scaled by d
    const unsigned short* hrow = hs1 + (long long)n * 128 + g * 8;
#pragma unroll
    for (int ks = 0; ks < 4; ++ks) {
      float v[8];
      bf8_to_f32(*(const uint4*)(hrow + ks * 32), v);
#pragma unroll
      for (int t = 0; t < 8; ++t) acc[ks][t] = d * v[t];
    }
  } else {
#pragma unroll
    for (int ks = 0; ks < 4; ++ks)
#pragma unroll
      for (int t = 0; t < 8; ++t) acc[ks][t] = 0.f;
  }

  // this wave's edge slots: wid, wid+2, wid+4, ... < m   (unroll 2)
  int j = wid;
  for (; j + 2 < m; j += 4) {
    int s0 = csr16[base16 + j], s1 = csr16[base16 + j + 2];
    float d0 = rsqrtf((float)deg[s0] + 1.0f);
    float d1 = rsqrtf((float)deg[s1] + 1.0f);
    const unsigned short* p0 = hs1 + (long long)s0 * 128 + g * 8;
    const unsigned short* p1 = hs1 + (long long)s1 * 128 + g * 8;
#pragma unroll
    for (int ks = 0; ks < 4; ++ks) {
      float v0[8], v1[8];
      bf8_to_f32(*(const uint4*)(p0 + ks * 32), v0);
      bf8_to_f32(*(const uint4*)(p1 + ks * 32), v1);
#pragma unroll
      for (int t = 0; t < 8; ++t)
        acc[ks][t] = fmaf(d1, v1[t], fmaf(d0, v0[t], acc[ks][t]));
    }
  }
  if (j < m) {
    int s0 = csr16[base16 + j];
    float d0 = rsqrtf((float)deg[s0] + 1.0f);
    const unsigned short* p0 = hs1 + (long long)s0 * 128 + g * 8;
#pragma unroll
    for (int ks = 0; ks < 4; ++ks) {
      float v0[8];
      bf8_to_f32(*(const uint4*)(p0 + ks * 32), v0);
#pragma unroll
      for (int t = 0; t < 8; ++t) acc[ks][t] = fmaf(d0, v0[t], acc[ks][t]);
    }
  }
  if (wid == 0 && dg > CAP) {  // rare: spill scan
    int ns = min(*nspill, SPILL_CAP);
    for (int i = 0; i < ns; ++i) {
      int2 p = spill[i];
      if (p.y == n) {
        float d0 = rsqrtf((float)deg[p.x] + 1.0f);
        const unsigned short* p0 = hs1 + (long long)p.x * 128 + g * 8;
#pragma unroll
        for (int ks = 0; ks < 4; ++ks) {
          float v0[8];
          bf8_to_f32(*(const uint4*)(p0 + ks * 32), v0);
#pragma unroll
          for (int t = 0; t < 8; ++t) acc[ks][t] = fmaf(d0, v0[t], acc[ks][t]);
        }
      }
    }
  }

  // combine: wave 1 -> LDS, wave 0 adds
  if (wid == 1) {
#pragma unroll
    for (int ks = 0; ks < 4; ++ks)
#pragma unroll
      for (int t = 0; t < 8; ++t) part[lane][ks * 8 + t] = acc[ks][t];
  }
  __syncthreads();
  if (wid == 1) return;
#pragma unroll
  for (int ks = 0; ks < 4; ++ks)
#pragma unroll
    for (int t = 0; t < 8; ++t) acc[ks][t] += part[lane][ks * 8 + t];

  // agg1 row slice = relu(b1 + d*acc) -> bf16 A-fragments
  union { bf16x8 v; uint32_t u[4]; } av[4];
#pragma unroll
  for (int ks = 0; ks < 4; ++ks) {
    float4 bv0 = *(const float4*)&b1[ks * 32 + g * 8];
    float4 bv1 = *(const float4*)&b1[ks * 32 + g * 8 + 4];
    float r8[8];
    r8[0] = fmaxf(bv0.x + d * acc[ks][0], 0.f);
    r8[1] = fmaxf(bv0.y + d * acc[ks][1], 0.f);
    r8[2] = fmaxf(bv0.z + d * acc[ks][2], 0.f);
    r8[3] = fmaxf(bv0.w + d * acc[ks][3], 0.f);
    r8[4] = fmaxf(bv1.x + d * acc[ks][4], 0.f);
    r8[5] = fmaxf(bv1.y + d * acc[ks][5], 0.f);
    r8[6] = fmaxf(bv1.z + d * acc[ks][6], 0.f);
    r8[7] = fmaxf(bv1.w + d * acc[ks][7], 0.f);
    av[ks].u[0] = cvt_pk_bf16(r8[0], r8[1]);
    av[ks].u[1] = cvt_pk_bf16(r8[2], r8[3]);
    av[ks].u[2] = cvt_pk_bf16(r8[4], r8[5]);
    av[ks].u[3] = cvt_pk_bf16(r8[6], r8[7]);
  }

  // layer-2 MFMA: hs2 stripe = dinv * (agg1 @ W2)   (hs2 pre-scaled)
  f32x4 accm[4];
#pragma unroll
  for (int nt = 0; nt < 4; ++nt) accm[nt] = (f32x4){0.f, 0.f, 0.f, 0.f};
  const bf16x8* wf = (const bf16x8*)wfrag2;
#pragma unroll
  for (int ks = 0; ks < 4; ++ks) {
#pragma unroll
    for (int nt = 0; nt < 4; ++nt) {
      bf16x8 bf = wf[(ks * 4 + nt) * 64 + lane];
      accm[nt] = __builtin_amdgcn_mfma_f32_16x16x32_bf16(av[ks].v, bf, accm[nt], 0, 0, 0);
    }
  }

#pragma unroll
  for (int r = 0; r < 4; ++r) {
    int row = rb + g * 4 + r;
    float sc = rsqrtf((float)deg[row] + 1.0f);
#pragma unroll
    for (int nt = 0; nt < 4; ++nt) {
      float val = accm[nt][r] * sc;
      hs2[(long long)row * 64 + nt * 16 + c] = (unsigned short)cvt_pk_bf16(val, val);
    }
  }
}

// ---- final gather: out[n] = b2 + d_n*(hs2[n] + sum_src hs2[src]), f32 out ----
// hs2 rows pre-scaled by their own dinv -> no per-src scale here.

__global__ __launch_bounds__(256) void k_gather_out(
    const int* __restrict__ deg, const int* __restrict__ csr16,
    const int* __restrict__ nspill, const int2* __restrict__ spill,
    const unsigned short* __restrict__ hs, const float* __restrict__ bias,
    float* __restrict__ out) {
  constexpr int C = 64, Q = 8;
  int idx = blockIdx.x * 256 + threadIdx.x;
  if (idx >= N_NODES * Q) return;
  int n = idx / Q, q = idx % Q;
  int dg = deg[n];
  int m = min(dg, CAP);
  int base16 = n * CAP;
  float d = rsqrtf((float)dg + 1.0f);

  float acc[8];
  bf8_to_f32(*(const uint4*)&hs[(long long)n * C + q * 8], acc);  // self

  int j = 0;
  for (; j + 2 <= m; j += 2) {
    int s0 = csr16[base16 + j], s1 = csr16[base16 + j + 1];
    uint4 u0 = *(const uint4*)&hs[(long long)s0 * C + q * 8];
    uint4 u1 = *(const uint4*)&hs[(long long)s1 * C + q * 8];
    float v0[8], v1[8];
    bf8_to_f32(u0, v0);
    bf8_to_f32(u1, v1);
#pragma unroll
    for (int t = 0; t < 8; ++t) acc[t] += v0[t] + v1[t];
  }
  if (j < m) {
    float v0[8];
    bf8_to_f32(*(const uint4*)&hs[(long long)csr16[base16 + j] * C + q * 8], v0);
#pragma unroll
    for (int t = 0; t < 8; ++t) acc[t] += v0[t];
  }
  if (dg > CAP) {
    int ns = min(*nspill, SPILL_CAP);
    for (int i = 0; i < ns; ++i) {
      int2 p = spill[i];
      if (p.y == n) {
        float v0[8];
        bf8_to_f32(*(const uint4*)&hs[(long long)p.x * C + q * 8], v0);
#pragma unroll
        for (int t = 0; t < 8; ++t) acc[t] += v0[t];
      }
    }
  }

  float4 bv0 = *(const float4*)&bias[q * 8];
  float4 bv1 = *(const float4*)&bias[q * 8 + 4];
  float4 o0 = {bv0.x + d * acc[0], bv0.y + d * acc[1], bv0.z + d * acc[2],
               bv0.w + d * acc[3]};
  float4 o1 = {bv1.x + d * acc[4], bv1.y + d * acc[5], bv1.z + d * acc[6],
               bv1.w + d * acc[7]};
  *(float4*)&out[(long long)n * C + q * 8] = o0;
  *(float4*)&out[(long long)n * C + q * 8 + 4] = o1;
}

// ---------------- launch (4 dispatches) ----------------

extern "C" void kernel_launch(void* const* d_in, const int* in_sizes, int n_in,
                              void* d_out, int out_size, void* d_ws, size_t ws_size,
                              hipStream_t stream) {
  const float* x = (const float*)d_in[0];
  const int* ei = (const int*)d_in[1];
  const int* erow = ei;            // sources
  const int* ecol = ei + N_EDGES;  // targets
  const float* W1 = (const float*)d_in[2];
  const float* b1 = (const float*)d_in[3];
  const float* W2 = (const float*)d_in[4];
  const float* b2 = (const float*)d_in[5];
  float* out = (float*)d_out;

  char* ws = (char*)d_ws;
  // deg + nspill contiguous (zeroed by k_wprep_zero)
  int* deg = (int*)(ws + 0);                      // 400,000 B
  int* nspill = (int*)(ws + 400000);              // 64 B
  int* csr16 = (int*)(ws + 400064);               // 6,400,000 B (64B-aligned)
  int2* spill = (int2*)(ws + 6800064);            // 524,288 B
  unsigned short* hs1 = (unsigned short*)(ws + 7324352);   // 25.6 MB (bf16)
  unsigned short* hs2 = (unsigned short*)(ws + 32924352);  // 12.8 MB (bf16)
  uint4* wfrag1 = (uint4*)(ws + 45724352);        // 32 KB
  uint4* wfrag2 = (uint4*)(ws + 45757120);        // 16 KB

  // 1: W fragment packing + zero deg/nspill (stream-ordered before dispatch 2)
  k_wprep_zero<<<(3072 + N_NODES + 16 + 255) / 256, 256, 0, stream>>>(W1, W2, wfrag1,
                                                                      wfrag2, deg);
  // 2: hist+fill (4 edges/thread, int4 loads) ∥ layer-1 GEMM, interleaved 2:5
  k_histfill_gemm1<<<UGRID, 256, 0, stream>>>(erow, ecol, deg, csr16, nspill, spill, x,
                                              wfrag1, hs1);
  // 3: fused layer-1 aggregation + layer-2 GEMM; 2 waves / stripe (r20 form)
  k_gather_gemm2<<<ROWTILES, 128, 0, stream>>>(deg, csr16, nspill, spill, hs1, b1,
                                               wfrag2, hs2);
  // 4: final aggregation -> out (f32)
  k_gather_out<<<N_NODES * 8 / 256, 256, 0, stream>>>(deg, csr16, nspill, spill, hs2,
                                                      b2, out);
}